// Round 1
// baseline (1650.803 us; speedup 1.0000x reference)
//
#include <hip/hip_runtime.h>

// LstmSequential: tokens[4096,80] -> emb gather -> LSTM(64) -> LSTM(64) -> dense(1) -> sigmoid
// Round 1: fused single kernel, fp32 everywhere, weights streamed from global (L2).
// lane = hidden unit (64 lanes = 64 units), R=2 batch rows per wave for weight reuse.
// 256 blocks x 512 threads (8 waves) -> 16 rows/block, 4096 rows total. No workspace.

#define VOCAB 10000
#define EMB 100
#define UNITS 64
#define SEQ 80
#define BATCH 4096
#define NG 4
#define R 2
#define WAVES_PER_BLOCK 8
#define ROWS_PER_BLOCK (R * WAVES_PER_BLOCK)   // 16
#define NBLOCKS (BATCH / ROWS_PER_BLOCK)       // 256

__device__ __forceinline__ float sigm(float x) {
    return 1.0f / (1.0f + __expf(-x));
}
__device__ __forceinline__ float tanh_fast(float x) {
    // tanh(x) = 2*sigmoid(2x) - 1
    return 2.0f / (1.0f + __expf(-2.0f * x)) - 1.0f;
}
// broadcast lane j's value to all lanes via v_readlane (VALU/SGPR path, avoids LDS pipe)
__device__ __forceinline__ float lane_bcast(float v, int j) {
    return __builtin_bit_cast(float, __builtin_amdgcn_readlane(__builtin_bit_cast(int, v), j));
}

__global__ __launch_bounds__(512) void lstm_fused_kernel(
    const int* __restrict__ tokens,
    const float* __restrict__ emb,
    const float* __restrict__ W1, const float* __restrict__ U1, const float* __restrict__ b1,
    const float* __restrict__ W2, const float* __restrict__ U2, const float* __restrict__ b2,
    const float* __restrict__ Wd, const float* __restrict__ bd,
    float* __restrict__ out)
{
    const int lane = threadIdx.x & 63;
    const int wave = threadIdx.x >> 6;
    const int row0 = blockIdx.x * ROWS_PER_BLOCK + wave * R;  // rows row0, row0+1

    // hoisted per-lane constants
    float bias1[NG], bias2[NG];
#pragma unroll
    for (int g = 0; g < NG; ++g) {
        bias1[g] = b1[g * UNITS + lane];
        bias2[g] = b2[g * UNITS + lane];
    }
    const float wd  = Wd[lane];
    const float bdv = bd[0];

    // recurrent state: lane u holds unit u's h/c for R rows
    float h1[R] = {0.f, 0.f}, c1[R] = {0.f, 0.f};
    float h2[R] = {0.f, 0.f}, c2[R] = {0.f, 0.f};

#pragma unroll 1
    for (int t = 0; t < SEQ; ++t) {
        // ---------------- layer 1: z = x@W1 + h1@U1 + b1 ----------------
        float acc[NG][R];
#pragma unroll
        for (int g = 0; g < NG; ++g)
#pragma unroll
            for (int r = 0; r < R; ++r) acc[g][r] = bias1[g];

        // x part — embedding rows are wave-uniform addresses (token per row)
        int tokA = __builtin_amdgcn_readfirstlane(tokens[(row0 + 0) * SEQ + t]);
        int tokB = __builtin_amdgcn_readfirstlane(tokens[(row0 + 1) * SEQ + t]);
        const float4* xA = (const float4*)(emb + (size_t)tokA * EMB);  // 400B rows, 16B aligned
        const float4* xB = (const float4*)(emb + (size_t)tokB * EMB);

#pragma unroll 5
        for (int d4 = 0; d4 < EMB / 4; ++d4) {
            float4 a4 = xA[d4];
            float4 b4 = xB[d4];
            float av[4] = {a4.x, a4.y, a4.z, a4.w};
            float bv[4] = {b4.x, b4.y, b4.z, b4.w};
#pragma unroll
            for (int e = 0; e < 4; ++e) {
                const int d = d4 * 4 + e;
                const float* wrow = W1 + d * (NG * UNITS);
#pragma unroll
                for (int g = 0; g < NG; ++g) {
                    float w = wrow[g * UNITS + lane];     // coalesced across lanes
                    acc[g][0] += av[e] * w;
                    acc[g][1] += bv[e] * w;
                }
            }
        }

        // h1 part
#pragma unroll 4
        for (int j = 0; j < UNITS; ++j) {
            float ha = lane_bcast(h1[0], j);
            float hb = lane_bcast(h1[1], j);
            const float* urow = U1 + j * (NG * UNITS);
#pragma unroll
            for (int g = 0; g < NG; ++g) {
                float w = urow[g * UNITS + lane];
                acc[g][0] += ha * w;
                acc[g][1] += hb * w;
            }
        }

        // gates layer 1 (order i, f, g, o)
#pragma unroll
        for (int r = 0; r < R; ++r) {
            float ig = sigm(acc[0][r]);
            float fg = sigm(acc[1][r]);
            float gg = tanh_fast(acc[2][r]);
            float og = sigm(acc[3][r]);
            c1[r] = fg * c1[r] + ig * gg;
            h1[r] = og * tanh_fast(c1[r]);
        }

        // ---------------- layer 2: z = h1@W2 + h2@U2 + b2 ----------------
        float acc2[NG][R];
#pragma unroll
        for (int g = 0; g < NG; ++g)
#pragma unroll
            for (int r = 0; r < R; ++r) acc2[g][r] = bias2[g];

#pragma unroll 4
        for (int j = 0; j < UNITS; ++j) {
            float pa = lane_bcast(h1[0], j);
            float pb = lane_bcast(h1[1], j);
            float qa = lane_bcast(h2[0], j);
            float qb = lane_bcast(h2[1], j);
            const float* w2row = W2 + j * (NG * UNITS);
            const float* u2row = U2 + j * (NG * UNITS);
#pragma unroll
            for (int g = 0; g < NG; ++g) {
                float w2 = w2row[g * UNITS + lane];
                float u2 = u2row[g * UNITS + lane];
                acc2[g][0] += pa * w2;
                acc2[g][1] += pb * w2;
                acc2[g][0] += qa * u2;
                acc2[g][1] += qb * u2;
            }
        }

#pragma unroll
        for (int r = 0; r < R; ++r) {
            float ig = sigm(acc2[0][r]);
            float fg = sigm(acc2[1][r]);
            float gg = tanh_fast(acc2[2][r]);
            float og = sigm(acc2[3][r]);
            c2[r] = fg * c2[r] + ig * gg;
            h2[r] = og * tanh_fast(c2[r]);
        }
    }

    // ---------------- head: sigmoid(h2_last @ Wd + bd) ----------------
#pragma unroll
    for (int r = 0; r < R; ++r) {
        float p = h2[r] * wd;
#pragma unroll
        for (int off = 32; off > 0; off >>= 1) p += __shfl_down(p, off, 64);
        if (lane == 0) out[row0 + r] = sigm(p + bdv);
    }
}

extern "C" void kernel_launch(void* const* d_in, const int* in_sizes, int n_in,
                              void* d_out, int out_size, void* d_ws, size_t ws_size,
                              hipStream_t stream) {
    const int*   tokens = (const int*)  d_in[0];
    const float* emb    = (const float*)d_in[1];
    const float* W1     = (const float*)d_in[2];
    const float* U1     = (const float*)d_in[3];
    const float* b1     = (const float*)d_in[4];
    const float* W2     = (const float*)d_in[5];
    const float* U2     = (const float*)d_in[6];
    const float* b2     = (const float*)d_in[7];
    const float* Wd     = (const float*)d_in[8];
    const float* bd     = (const float*)d_in[9];
    float* out = (float*)d_out;

    lstm_fused_kernel<<<NBLOCKS, WAVES_PER_BLOCK * 64, 0, stream>>>(
        tokens, emb, W1, U1, b1, W2, U2, b2, Wd, bd, out);
}

// Round 2
// 709.737 us; speedup vs baseline: 2.3259x; 2.3259x over previous
//
#include <hip/hip_runtime.h>

// LstmSequential round 2: weight-motion elimination.
//   K0 prep_weights: pack U1 / W1 / [W2;U2] into fp16 k-pair-packed, [kp][col] layout (ws)
//   K1 compute_e1 : E1[v][c] = b1[c] + emb[v]@W1  (x@W1 collapses to a table gather)
//   K2 lstm1      : layer-1 recurrence, U1 fp16 in 128 persistent VGPRs, h via readlane+dot2,
//                   writes H1 packed fp16 to ws
//   K3 lstm2_head : layer-2 recurrence ([W2;U2] fp16 in 256 persistent VGPRs) + dense head
// Fallback to round-1 monolithic kernel if ws_size too small.

#define VOCAB 10000
#define EMB   100
#define UNITS 64
#define SEQ   80
#define BATCH 4096
#define NG    4

typedef _Float16 half2_t __attribute__((ext_vector_type(2)));
typedef unsigned int uint;

__device__ __forceinline__ float sigm(float x)  { return 1.0f / (1.0f + __expf(-x)); }
__device__ __forceinline__ float tanhf_(float x){ return 2.0f / (1.0f + __expf(-2.0f * x)) - 1.0f; }
__device__ __forceinline__ uint  rl_u(uint v, int l) { return (uint)__builtin_amdgcn_readlane((int)v, l); }
__device__ __forceinline__ uint  pack2(float lo, float hi) {
    return __builtin_bit_cast(uint, __builtin_amdgcn_cvt_pkrtz(lo, hi));
}
__device__ __forceinline__ float dot2(uint a, uint b, float c) {
    return __builtin_amdgcn_fdot2(__builtin_bit_cast(half2_t, a), __builtin_bit_cast(half2_t, b), c, false);
}

// ---------------- workspace layout (bytes) ----------------
#define WS_E1_OFF   0                       // 10000*256 fp32 = 10,240,000
#define WS_W1P_OFF  10240000                // 50*256 uint    =     51,200
#define WS_U1P_OFF  10291200                // 32*256 uint    =     32,768
#define WS_WU2P_OFF 10323968                // 64*256 uint    =     65,536
#define WS_H1P_OFF  10389504                // 4096*80*32 uint= 41,943,040
#define WS_NEEDED   52332544

// ---------------- K0: pack weights to fp16 pairs, [kp][256] layout ----------------
__global__ void prep_weights(const float* __restrict__ W1, const float* __restrict__ U1,
                             const float* __restrict__ W2, const float* __restrict__ U2,
                             uint* __restrict__ W1p, uint* __restrict__ U1p,
                             uint* __restrict__ WU2p) {
    int idx = blockIdx.x * 256 + threadIdx.x;
    if (idx < 50 * 256) {                       // W1: k=100 -> 50 pairs
        int kp = idx >> 8, c = idx & 255;
        W1p[kp * 256 + c] = pack2(W1[(2 * kp) * 256 + c], W1[(2 * kp + 1) * 256 + c]);
    }
    if (idx < 32 * 256) {                       // U1: k=64 -> 32 pairs
        int kp = idx >> 8, c = idx & 255;
        U1p[kp * 256 + c] = pack2(U1[(2 * kp) * 256 + c], U1[(2 * kp + 1) * 256 + c]);
    }
    if (idx < 64 * 256) {                       // [W2;U2]: k=128 -> 64 pairs
        int kp = idx >> 8, c = idx & 255;
        float lo, hi;
        if (kp < 32) { lo = W2[(2 * kp) * 256 + c];        hi = W2[(2 * kp + 1) * 256 + c]; }
        else         { int k2 = 2 * (kp - 32);
                       lo = U2[k2 * 256 + c];              hi = U2[(k2 + 1) * 256 + c]; }
        WU2p[kp * 256 + c] = pack2(lo, hi);
    }
}

// ---------------- K1: E1 = emb @ W1 + b1 ----------------
__global__ __launch_bounds__(256) void compute_e1(
    const float* __restrict__ emb, const uint* __restrict__ W1p,
    const float* __restrict__ b1, float* __restrict__ E1) {
    const int lane = threadIdx.x & 63;
    const int c    = threadIdx.x;            // col 0..255
    uint w[50];
#pragma unroll
    for (int kp = 0; kp < 50; ++kp) w[kp] = W1p[kp * 256 + c];
    const float bias = b1[c];
    for (int v = blockIdx.x; v < VOCAB; v += gridDim.x) {
        uint ep = 0;
        if (lane < 50) ep = pack2(emb[v * EMB + 2 * lane], emb[v * EMB + 2 * lane + 1]);
        float acc = bias;
#pragma unroll
        for (int kp = 0; kp < 50; ++kp) acc = dot2(w[kp], rl_u(ep, kp), acc);
        E1[v * 256 + c] = acc;
    }
}

// ---------------- K2: layer-1 recurrence ----------------
#define KB_R 2
__global__ __launch_bounds__(512, 2) void lstm1(
    const int* __restrict__ tokens, const float* __restrict__ E1,
    const uint* __restrict__ U1p, uint* __restrict__ H1p) {
    const int lane = threadIdx.x & 63;
    const int wave = threadIdx.x >> 6;
    const int row0 = blockIdx.x * (8 * KB_R) + wave * KB_R;

    uint w[NG][32];                          // U1 fp16 pairs, persistent in VGPRs
#pragma unroll
    for (int g = 0; g < NG; ++g)
#pragma unroll
        for (int kp = 0; kp < 32; ++kp) w[g][kp] = U1p[kp * 256 + g * 64 + lane];

    float h[KB_R] = {0.f, 0.f}, cc[KB_R] = {0.f, 0.f};
    uint  hp[KB_R] = {0u, 0u};

    // prefetch t=0 E1 rows
    float epre[NG][KB_R];
    int   tok[KB_R];
#pragma unroll
    for (int r = 0; r < KB_R; ++r) tok[r] = tokens[(row0 + r) * SEQ];
#pragma unroll
    for (int r = 0; r < KB_R; ++r)
#pragma unroll
        for (int g = 0; g < NG; ++g) epre[g][r] = E1[tok[r] * 256 + g * 64 + lane];

#pragma unroll 1
    for (int t = 0; t < SEQ; ++t) {
        float acc[NG][KB_R];
#pragma unroll
        for (int g = 0; g < NG; ++g)
#pragma unroll
            for (int r = 0; r < KB_R; ++r) acc[g][r] = epre[g][r];

        if (t + 1 < SEQ) {                   // prefetch next step's E1 rows
#pragma unroll
            for (int r = 0; r < KB_R; ++r) tok[r] = tokens[(row0 + r) * SEQ + t + 1];
#pragma unroll
            for (int r = 0; r < KB_R; ++r)
#pragma unroll
                for (int g = 0; g < NG; ++g) epre[g][r] = E1[tok[r] * 256 + g * 64 + lane];
        }

#pragma unroll
        for (int kp = 0; kp < 32; ++kp) {
            uint hh[KB_R];
#pragma unroll
            for (int r = 0; r < KB_R; ++r) hh[r] = rl_u(hp[r], kp);
#pragma unroll
            for (int g = 0; g < NG; ++g)
#pragma unroll
                for (int r = 0; r < KB_R; ++r) acc[g][r] = dot2(w[g][kp], hh[r], acc[g][r]);
        }

#pragma unroll
        for (int r = 0; r < KB_R; ++r) {
            float ig = sigm(acc[0][r]);
            float fg = sigm(acc[1][r]);
            float gg = tanhf_(acc[2][r]);
            float og = sigm(acc[3][r]);
            cc[r] = fg * cc[r] + ig * gg;
            h[r]  = og * tanhf_(cc[r]);
            float lo = __shfl(h[r], 2 * lane, 64);
            float hi = __shfl(h[r], 2 * lane + 1, 64);
            hp[r] = pack2(lo, hi);           // lanes 0..31 hold the 32 k-pairs
            if (lane < 32) H1p[((row0 + r) * SEQ + t) * 32 + lane] = hp[r];
        }
    }
}

// ---------------- K3: layer-2 recurrence + dense head ----------------
#define KC_R 4
__global__ __launch_bounds__(256, 1) void lstm2_head(
    const uint* __restrict__ WU2p, const float* __restrict__ b2,
    const uint* __restrict__ H1p, const float* __restrict__ Wd,
    const float* __restrict__ bd, float* __restrict__ out) {
    const int lane = threadIdx.x & 63;
    const int wave = threadIdx.x >> 6;
    const int row0 = blockIdx.x * (4 * KC_R) + wave * KC_R;

    uint w[NG][64];                          // [W2;U2] fp16 pairs, persistent in VGPRs
#pragma unroll
    for (int g = 0; g < NG; ++g)
#pragma unroll
        for (int kp = 0; kp < 64; ++kp) w[g][kp] = WU2p[kp * 256 + g * 64 + lane];

    float bias[NG];
#pragma unroll
    for (int g = 0; g < NG; ++g) bias[g] = b2[g * 64 + lane];

    float h[KC_R] = {0.f, 0.f, 0.f, 0.f}, cc[KC_R] = {0.f, 0.f, 0.f, 0.f};
    uint  hp[KC_R] = {0u, 0u, 0u, 0u};

    uint h1n[KC_R];                          // prefetched h1 pairs for step t
#pragma unroll
    for (int r = 0; r < KC_R; ++r) h1n[r] = H1p[((row0 + r) * SEQ) * 32 + (lane & 31)];

#pragma unroll 1
    for (int t = 0; t < SEQ; ++t) {
        uint h1c[KC_R];
#pragma unroll
        for (int r = 0; r < KC_R; ++r) h1c[r] = h1n[r];
        if (t + 1 < SEQ) {
#pragma unroll
            for (int r = 0; r < KC_R; ++r)
                h1n[r] = H1p[((row0 + r) * SEQ + t + 1) * 32 + (lane & 31)];
        }

        float acc[NG][KC_R];
#pragma unroll
        for (int g = 0; g < NG; ++g)
#pragma unroll
            for (int r = 0; r < KC_R; ++r) acc[g][r] = bias[g];

#pragma unroll
        for (int kp = 0; kp < 64; ++kp) {
            uint hh[KC_R];
#pragma unroll
            for (int r = 0; r < KC_R; ++r)
                hh[r] = (kp < 32) ? rl_u(h1c[r], kp) : rl_u(hp[r], kp - 32);
#pragma unroll
            for (int g = 0; g < NG; ++g)
#pragma unroll
                for (int r = 0; r < KC_R; ++r) acc[g][r] = dot2(w[g][kp], hh[r], acc[g][r]);
        }

#pragma unroll
        for (int r = 0; r < KC_R; ++r) {
            float ig = sigm(acc[0][r]);
            float fg = sigm(acc[1][r]);
            float gg = tanhf_(acc[2][r]);
            float og = sigm(acc[3][r]);
            cc[r] = fg * cc[r] + ig * gg;
            h[r]  = og * tanhf_(cc[r]);
            float lo = __shfl(h[r], 2 * lane, 64);
            float hi = __shfl(h[r], 2 * lane + 1, 64);
            hp[r] = pack2(lo, hi);
        }
    }

    const float wd  = Wd[lane];
    const float bdv = bd[0];
#pragma unroll
    for (int r = 0; r < KC_R; ++r) {
        float p = h[r] * wd;
#pragma unroll
        for (int off = 32; off > 0; off >>= 1) p += __shfl_down(p, off, 64);
        if (lane == 0) out[row0 + r] = sigm(p + bdv);
    }
}

// ---------------- fallback: round-1 monolithic kernel ----------------
__device__ __forceinline__ float lane_bcast(float v, int j) {
    return __builtin_bit_cast(float, __builtin_amdgcn_readlane(__builtin_bit_cast(int, v), j));
}

__global__ __launch_bounds__(512) void lstm_fused_fallback(
    const int* __restrict__ tokens, const float* __restrict__ emb,
    const float* __restrict__ W1, const float* __restrict__ U1, const float* __restrict__ b1,
    const float* __restrict__ W2, const float* __restrict__ U2, const float* __restrict__ b2,
    const float* __restrict__ Wd, const float* __restrict__ bd, float* __restrict__ out) {
    const int lane = threadIdx.x & 63;
    const int wave = threadIdx.x >> 6;
    const int row0 = blockIdx.x * 16 + wave * 2;
    float bias1[NG], bias2[NG];
#pragma unroll
    for (int g = 0; g < NG; ++g) { bias1[g] = b1[g * 64 + lane]; bias2[g] = b2[g * 64 + lane]; }
    const float wd = Wd[lane]; const float bdv = bd[0];
    float h1[2] = {0.f, 0.f}, c1[2] = {0.f, 0.f}, h2[2] = {0.f, 0.f}, c2[2] = {0.f, 0.f};
#pragma unroll 1
    for (int t = 0; t < SEQ; ++t) {
        float acc[NG][2];
#pragma unroll
        for (int g = 0; g < NG; ++g) { acc[g][0] = bias1[g]; acc[g][1] = bias1[g]; }
        int tokA = __builtin_amdgcn_readfirstlane(tokens[(row0 + 0) * SEQ + t]);
        int tokB = __builtin_amdgcn_readfirstlane(tokens[(row0 + 1) * SEQ + t]);
        const float4* xA = (const float4*)(emb + (size_t)tokA * EMB);
        const float4* xB = (const float4*)(emb + (size_t)tokB * EMB);
#pragma unroll 5
        for (int d4 = 0; d4 < EMB / 4; ++d4) {
            float4 a4 = xA[d4]; float4 b4 = xB[d4];
            float av[4] = {a4.x, a4.y, a4.z, a4.w}; float bv[4] = {b4.x, b4.y, b4.z, b4.w};
#pragma unroll
            for (int e = 0; e < 4; ++e) {
                const float* wrow = W1 + (d4 * 4 + e) * 256;
#pragma unroll
                for (int g = 0; g < NG; ++g) {
                    float wv = wrow[g * 64 + lane];
                    acc[g][0] += av[e] * wv; acc[g][1] += bv[e] * wv;
                }
            }
        }
#pragma unroll 4
        for (int j = 0; j < UNITS; ++j) {
            float ha = lane_bcast(h1[0], j), hb = lane_bcast(h1[1], j);
            const float* urow = U1 + j * 256;
#pragma unroll
            for (int g = 0; g < NG; ++g) {
                float wv = urow[g * 64 + lane];
                acc[g][0] += ha * wv; acc[g][1] += hb * wv;
            }
        }
#pragma unroll
        for (int r = 0; r < 2; ++r) {
            float ig = sigm(acc[0][r]), fg = sigm(acc[1][r]);
            float gg = tanhf_(acc[2][r]), og = sigm(acc[3][r]);
            c1[r] = fg * c1[r] + ig * gg; h1[r] = og * tanhf_(c1[r]);
        }
        float acc2[NG][2];
#pragma unroll
        for (int g = 0; g < NG; ++g) { acc2[g][0] = bias2[g]; acc2[g][1] = bias2[g]; }
#pragma unroll 4
        for (int j = 0; j < UNITS; ++j) {
            float pa = lane_bcast(h1[0], j), pb = lane_bcast(h1[1], j);
            float qa = lane_bcast(h2[0], j), qb = lane_bcast(h2[1], j);
            const float* w2row = W2 + j * 256; const float* u2row = U2 + j * 256;
#pragma unroll
            for (int g = 0; g < NG; ++g) {
                float w2v = w2row[g * 64 + lane], u2v = u2row[g * 64 + lane];
                acc2[g][0] += pa * w2v + qa * u2v;
                acc2[g][1] += pb * w2v + qb * u2v;
            }
        }
#pragma unroll
        for (int r = 0; r < 2; ++r) {
            float ig = sigm(acc2[0][r]), fg = sigm(acc2[1][r]);
            float gg = tanhf_(acc2[2][r]), og = sigm(acc2[3][r]);
            c2[r] = fg * c2[r] + ig * gg; h2[r] = og * tanhf_(c2[r]);
        }
    }
#pragma unroll
    for (int r = 0; r < 2; ++r) {
        float p = h2[r] * wd;
#pragma unroll
        for (int off = 32; off > 0; off >>= 1) p += __shfl_down(p, off, 64);
        if (lane == 0) out[row0 + r] = sigm(p + bdv);
    }
}

extern "C" void kernel_launch(void* const* d_in, const int* in_sizes, int n_in,
                              void* d_out, int out_size, void* d_ws, size_t ws_size,
                              hipStream_t stream) {
    const int*   tokens = (const int*)  d_in[0];
    const float* emb    = (const float*)d_in[1];
    const float* W1     = (const float*)d_in[2];
    const float* U1     = (const float*)d_in[3];
    const float* b1     = (const float*)d_in[4];
    const float* W2     = (const float*)d_in[5];
    const float* U2     = (const float*)d_in[6];
    const float* b2     = (const float*)d_in[7];
    const float* Wd     = (const float*)d_in[8];
    const float* bd     = (const float*)d_in[9];
    float* out = (float*)d_out;

    if (ws_size < (size_t)WS_NEEDED) {   // workspace too small: safe fallback
        lstm_fused_fallback<<<256, 512, 0, stream>>>(tokens, emb, W1, U1, b1, W2, U2, b2, Wd, bd, out);
        return;
    }

    char* ws = (char*)d_ws;
    float* E1  = (float*)(ws + WS_E1_OFF);
    uint* W1p  = (uint*) (ws + WS_W1P_OFF);
    uint* U1p  = (uint*) (ws + WS_U1P_OFF);
    uint* WU2p = (uint*) (ws + WS_WU2P_OFF);
    uint* H1p  = (uint*) (ws + WS_H1P_OFF);

    prep_weights<<<64, 256, 0, stream>>>(W1, U1, W2, U2, W1p, U1p, WU2p);
    compute_e1 <<<256, 256, 0, stream>>>(emb, W1p, b1, E1);
    lstm1      <<<256, 512, 0, stream>>>(tokens, E1, U1p, H1p);
    lstm2_head <<<256, 256, 0, stream>>>(WU2p, b2, H1p, Wd, bd, out);
}

// Round 3
// 255.497 us; speedup vs baseline: 6.4611x; 2.7779x over previous
//
#include <hip/hip_runtime.h>

// LstmSequential round 3: MFMA recurrence.
//  prep       : pack W1 (for e1), and U1 / [W2;U2] into MFMA B-fragment layout (fp16)
//  compute_e1 : E1r[v][u][gate] = b1 + emb[v]@W1   (x@W1 -> table gather, gate-interleaved)
//  lstm_mfma  : both LSTM layers + head fused. 256 blocks x 4 waves, 16 rows/block.
//               wave w owns cols {g*64 + w*16 ..+15} for ALL gates g -> c/h update is
//               lane-local (no z exchange). h crosses waves via 4KB LDS A-fragment buffer.
// Fallback to round-1 monolithic kernel if ws too small.

#define VOCAB 10000
#define EMB   100
#define SEQ   80
#define BATCH 4096

typedef _Float16 f16;
typedef _Float16 f16x8 __attribute__((ext_vector_type(8)));
typedef float    f32x4 __attribute__((ext_vector_type(4)));
typedef unsigned int uint;

__device__ __forceinline__ float sigm(float x)  { return 1.0f / (1.0f + __expf(-x)); }
__device__ __forceinline__ float tanh_(float x) { return 2.0f / (1.0f + __expf(-2.0f * x)) - 1.0f; }
__device__ __forceinline__ uint  pack2(float lo, float hi) {
    return __builtin_bit_cast(uint, __builtin_amdgcn_cvt_pkrtz(lo, hi));
}
__device__ __forceinline__ uint rl_u(uint v, int l) { return (uint)__builtin_amdgcn_readlane((int)v, l); }
typedef _Float16 half2_t __attribute__((ext_vector_type(2)));
__device__ __forceinline__ float dot2(uint a, uint b, float c) {
    return __builtin_amdgcn_fdot2(__builtin_bit_cast(half2_t, a), __builtin_bit_cast(half2_t, b), c, false);
}
__device__ __forceinline__ f32x4 mfma16(uint4 a, uint4 b, f32x4 c) {
    return __builtin_amdgcn_mfma_f32_16x16x32_f16(
        __builtin_bit_cast(f16x8, a), __builtin_bit_cast(f16x8, b), c, 0, 0, 0);
}

// ---------------- workspace layout (bytes) ----------------
#define WS_E1R_OFF 0                 // VOCAB*256 f32      = 10,240,000
#define WS_W1P_OFF 10240000          // 50*256 uint        = 51,200
#define WS_B1F_OFF 10291200          // 2048 uint4         = 32,768
#define WS_B2F_OFF 10323968          // 4096 uint4         = 65,536
#define WS_NEEDED  10389504

// ---------------- prep: pack weights ----------------
// B-frag element mapping (16x16x32 f16): lane holds B[k = kt*32 + (lane>>4)*8 + j][n = lane&15],
// j linear 0..7 across the uint4 (dword dw holds j=2dw lo, j=2dw+1 hi).
// Frag storage: B1f[((w*4+g)*2+kt)*64 + lane], B2f[((w*4+g)*4+kt)*64 + lane]  (uint4 each)
__global__ void prep(const float* __restrict__ W1, const float* __restrict__ U1,
                     const float* __restrict__ W2, const float* __restrict__ U2,
                     uint* __restrict__ W1p, uint* __restrict__ B1f, uint* __restrict__ B2f) {
    int idx = blockIdx.x * 256 + threadIdx.x;     // 64*256 = 16384 threads
    if (idx < 50 * 256) {                         // W1p [kp][256] for compute_e1
        int kp = idx >> 8, c = idx & 255;
        W1p[idx] = pack2(W1[(2 * kp) * 256 + c], W1[(2 * kp + 1) * 256 + c]);
    }
    if (idx < 8192) {                             // B1f dwords (U1, 64x256)
        int dw = idx & 3, lane = (idx >> 2) & 63, kt = (idx >> 8) & 1, g = (idx >> 9) & 3, w = idx >> 11;
        int k   = kt * 32 + (lane >> 4) * 8 + dw * 2;
        int col = g * 64 + w * 16 + (lane & 15);
        B1f[idx] = pack2(U1[k * 256 + col], U1[(k + 1) * 256 + col]);
    }
    if (idx < 16384) {                            // B2f dwords ([W2;U2], 128x256)
        int dw = idx & 3, lane = (idx >> 2) & 63, kt = (idx >> 8) & 3, g = (idx >> 10) & 3, w = idx >> 12;
        int k   = kt * 32 + (lane >> 4) * 8 + dw * 2;
        int col = g * 64 + w * 16 + (lane & 15);
        float lo = (k < 64) ? W2[k * 256 + col] : U2[(k - 64) * 256 + col];
        float hi = (k < 63) ? W2[(k + 1) * 256 + col] : U2[(k + 1 - 64) * 256 + col];
        B2f[idx] = pack2(lo, hi);
    }
}

// ---------------- E1r = emb @ W1 + b1, stored [v][u][gate] ----------------
__global__ __launch_bounds__(256) void compute_e1(
    const float* __restrict__ emb, const uint* __restrict__ W1p,
    const float* __restrict__ b1, float* __restrict__ E1r) {
    const int lane = threadIdx.x & 63;
    const int c    = threadIdx.x;                 // col 0..255 (= g*64+u)
    uint w[50];
#pragma unroll
    for (int kp = 0; kp < 50; ++kp) w[kp] = W1p[kp * 256 + c];
    const float bias = b1[c];
    for (int v = blockIdx.x; v < VOCAB; v += gridDim.x) {
        uint ep = 0;
        if (lane < 50) ep = pack2(emb[v * EMB + 2 * lane], emb[v * EMB + 2 * lane + 1]);
        float acc = bias;
#pragma unroll
        for (int kp = 0; kp < 50; ++kp) acc = dot2(w[kp], rl_u(ep, kp), acc);
        E1r[v * 256 + (c & 63) * 4 + (c >> 6)] = acc;
    }
}

// ---------------- fused 2-layer LSTM + head ----------------
// Abuf: fp16 A-matrix [16 m x 128 k] in fragment layout:
//   f16 index of (m,k) = ((k>>3)*16 + m)*8 + (k&7); lane's frag kt = uint4 at [kt*64 + lane].
//   k 0..63 = h1 (current), k 64..127 = h2 (previous/current).
__global__ __launch_bounds__(256, 1) void lstm_mfma(
    const int* __restrict__ tokens, const float* __restrict__ E1r,
    const uint4* __restrict__ B1f, const uint4* __restrict__ B2f,
    const float* __restrict__ b2, const float* __restrict__ Wd,
    const float* __restrict__ bd, float* __restrict__ out) {
    __shared__ uint4 AbufU[128];                  // 2048 f16 = 4 KB
    __shared__ float red[64];
    f16* Abuf = (f16*)AbufU;

    const int tid  = threadIdx.x;
    const int w    = tid >> 6;
    const int lane = tid & 63;
    const int q    = lane >> 4;
    const int li   = lane & 15;
    const int u    = w * 16 + li;                 // this lane's unit
    const int row0 = blockIdx.x * 16;

    // zero A buffer (h1=h2=0 at t=0)
    ((uint*)AbufU)[tid] = 0u; ((uint*)AbufU)[tid + 256] = 0u;
    ((uint*)AbufU)[tid + 512] = 0u; ((uint*)AbufU)[tid + 768] = 0u;

    // persistent B fragments
    uint4 b1f[4][2], b2f[4][4];
#pragma unroll
    for (int g = 0; g < 4; ++g) {
#pragma unroll
        for (int kt = 0; kt < 2; ++kt) b1f[g][kt] = B1f[((w * 4 + g) * 2 + kt) * 64 + lane];
#pragma unroll
        for (int kt = 0; kt < 4; ++kt) b2f[g][kt] = B2f[((w * 4 + g) * 4 + kt) * 64 + lane];
    }
    float b2v[4];
#pragma unroll
    for (int g = 0; g < 4; ++g) b2v[g] = b2[g * 64 + u];
    const float wdv = Wd[u];
    const float bdv = bd[0];

    // token windows (rows q*4+r), e1 prefetch for t=0
    int4 tokc[4], tokn[4];
    f32x4 e1c[4], e1n[4];
#pragma unroll
    for (int r = 0; r < 4; ++r) {
        tokc[r] = *(const int4*)(tokens + (size_t)(row0 + q * 4 + r) * SEQ);
        e1c[r]  = *(const f32x4*)(E1r + ((size_t)tokc[r].x * 64 + u) * 4);
    }

    float c1[4] = {0.f, 0.f, 0.f, 0.f}, c2[4] = {0.f, 0.f, 0.f, 0.f};
    float h2v[4] = {0.f, 0.f, 0.f, 0.f};

    __syncthreads();                              // Abuf zeros visible

#pragma unroll 1
    for (int t4 = 0; t4 < SEQ / 4; ++t4) {
        if (t4 < SEQ / 4 - 1) {
#pragma unroll
            for (int r = 0; r < 4; ++r)
                tokn[r] = *(const int4*)(tokens + (size_t)(row0 + q * 4 + r) * SEQ + (t4 + 1) * 4);
        }
#pragma unroll
        for (int s = 0; s < 4; ++s) {
            // ---- layer 1 MFMA: z1 = h1_{t-1} @ U1 ----
            f32x4 acc[4] = {{0,0,0,0},{0,0,0,0},{0,0,0,0},{0,0,0,0}};
            uint4 a0 = ((const uint4*)AbufU)[0 * 64 + lane];
            uint4 a1 = ((const uint4*)AbufU)[1 * 64 + lane];
#pragma unroll
            for (int g = 0; g < 4; ++g) acc[g] = mfma16(a0, b1f[g][0], acc[g]);
#pragma unroll
            for (int g = 0; g < 4; ++g) acc[g] = mfma16(a1, b1f[g][1], acc[g]);
            __syncthreads();                      // B1: all h1_{t-1} reads done

            // prefetch E1 for t+1
            if (t4 * 4 + s + 1 < SEQ) {
#pragma unroll
                for (int r = 0; r < 4; ++r) {
                    int tk = (s == 0) ? tokc[r].y : (s == 1) ? tokc[r].z
                           : (s == 2) ? tokc[r].w : tokn[r].x;
                    e1n[r] = *(const f32x4*)(E1r + ((size_t)tk * 64 + u) * 4);
                }
            }

            // ---- epilogue 1 (lane-local): rows q*4+r, unit u ----
#pragma unroll
            for (int r = 0; r < 4; ++r) {
                float zi = acc[0][r] + e1c[r][0];
                float zf = acc[1][r] + e1c[r][1];
                float zg = acc[2][r] + e1c[r][2];
                float zo = acc[3][r] + e1c[r][3];
                float ig = sigm(zi), fg = sigm(zf), gv = tanh_(zg), og = sigm(zo);
                c1[r] = fg * c1[r] + ig * gv;
                float h1 = og * tanh_(c1[r]);
                Abuf[((u >> 3) * 16 + q * 4 + r) * 8 + (u & 7)] = (f16)h1;
            }
            __syncthreads();                      // B2: h1_t visible

            // ---- layer 2 MFMA: z2 = [h1_t | h2_{t-1}] @ [W2;U2] ----
            f32x4 acc2[4] = {{0,0,0,0},{0,0,0,0},{0,0,0,0},{0,0,0,0}};
            uint4 a[4];
#pragma unroll
            for (int kt = 0; kt < 4; ++kt) a[kt] = ((const uint4*)AbufU)[kt * 64 + lane];
#pragma unroll
            for (int kt = 0; kt < 4; ++kt)
#pragma unroll
                for (int g = 0; g < 4; ++g) acc2[g] = mfma16(a[kt], b2f[g][kt], acc2[g]);
            __syncthreads();                      // B3: all h2_{t-1} reads done

            // ---- epilogue 2 (lane-local) ----
#pragma unroll
            for (int r = 0; r < 4; ++r) {
                float zi = acc2[0][r] + b2v[0];
                float zf = acc2[1][r] + b2v[1];
                float zg = acc2[2][r] + b2v[2];
                float zo = acc2[3][r] + b2v[3];
                float ig = sigm(zi), fg = sigm(zf), gv = tanh_(zg), og = sigm(zo);
                c2[r] = fg * c2[r] + ig * gv;
                float h2 = og * tanh_(c2[r]);
                h2v[r] = h2;
                Abuf[(8 + (u >> 3)) * 16 * 8 + (q * 4 + r) * 8 + (u & 7)] = (f16)h2;
            }
#pragma unroll
            for (int r = 0; r < 4; ++r) e1c[r] = e1n[r];
        }
        if (t4 < SEQ / 4 - 1) {
#pragma unroll
            for (int r = 0; r < 4; ++r) tokc[r] = tokn[r];
        }
    }

    // ---- head: out[row] = sigm(sum_u h2[row][u]*Wd[u] + bd) ----
#pragma unroll
    for (int r = 0; r < 4; ++r) {
        float p = h2v[r] * wdv;
        p += __shfl_xor(p, 1, 64);
        p += __shfl_xor(p, 2, 64);
        p += __shfl_xor(p, 4, 64);
        p += __shfl_xor(p, 8, 64);
        if (li == 0) red[w * 16 + q * 4 + r] = p;
    }
    __syncthreads();
    if (tid < 16) {
        float sum = red[tid] + red[16 + tid] + red[32 + tid] + red[48 + tid] + bdv;
        out[row0 + tid] = sigm(sum);
    }
}

// ---------------- fallback (no workspace): round-1 monolithic ----------------
__device__ __forceinline__ float lane_bcast(float v, int j) {
    return __builtin_bit_cast(float, __builtin_amdgcn_readlane(__builtin_bit_cast(int, v), j));
}
__global__ __launch_bounds__(512) void lstm_fused_fallback(
    const int* __restrict__ tokens, const float* __restrict__ emb,
    const float* __restrict__ W1, const float* __restrict__ U1, const float* __restrict__ b1,
    const float* __restrict__ W2, const float* __restrict__ U2, const float* __restrict__ b2,
    const float* __restrict__ Wd, const float* __restrict__ bd, float* __restrict__ out) {
    const int lane = threadIdx.x & 63;
    const int wave = threadIdx.x >> 6;
    const int row0 = blockIdx.x * 16 + wave * 2;
    float bias1[4], bias2[4];
#pragma unroll
    for (int g = 0; g < 4; ++g) { bias1[g] = b1[g * 64 + lane]; bias2[g] = b2[g * 64 + lane]; }
    const float wd = Wd[lane]; const float bdv = bd[0];
    float h1[2] = {0.f, 0.f}, c1[2] = {0.f, 0.f}, h2[2] = {0.f, 0.f}, c2[2] = {0.f, 0.f};
#pragma unroll 1
    for (int t = 0; t < SEQ; ++t) {
        float acc[4][2];
#pragma unroll
        for (int g = 0; g < 4; ++g) { acc[g][0] = bias1[g]; acc[g][1] = bias1[g]; }
        int tokA = __builtin_amdgcn_readfirstlane(tokens[(row0 + 0) * SEQ + t]);
        int tokB = __builtin_amdgcn_readfirstlane(tokens[(row0 + 1) * SEQ + t]);
        const float4* xA = (const float4*)(emb + (size_t)tokA * EMB);
        const float4* xB = (const float4*)(emb + (size_t)tokB * EMB);
#pragma unroll 5
        for (int d4 = 0; d4 < EMB / 4; ++d4) {
            float4 a4 = xA[d4]; float4 b4 = xB[d4];
            float av[4] = {a4.x, a4.y, a4.z, a4.w}; float bv[4] = {b4.x, b4.y, b4.z, b4.w};
#pragma unroll
            for (int e = 0; e < 4; ++e) {
                const float* wrow = W1 + (d4 * 4 + e) * 256;
#pragma unroll
                for (int g = 0; g < 4; ++g) {
                    float wv = wrow[g * 64 + lane];
                    acc[g][0] += av[e] * wv; acc[g][1] += bv[e] * wv;
                }
            }
        }
#pragma unroll 4
        for (int j = 0; j < 64; ++j) {
            float ha = lane_bcast(h1[0], j), hb = lane_bcast(h1[1], j);
            const float* urow = U1 + j * 256;
#pragma unroll
            for (int g = 0; g < 4; ++g) {
                float wv = urow[g * 64 + lane];
                acc[g][0] += ha * wv; acc[g][1] += hb * wv;
            }
        }
#pragma unroll
        for (int r = 0; r < 2; ++r) {
            float ig = sigm(acc[0][r]), fg = sigm(acc[1][r]);
            float gg = tanh_(acc[2][r]), og = sigm(acc[3][r]);
            c1[r] = fg * c1[r] + ig * gg; h1[r] = og * tanh_(c1[r]);
        }
        float acc2[4][2];
#pragma unroll
        for (int g = 0; g < 4; ++g) { acc2[g][0] = bias2[g]; acc2[g][1] = bias2[g]; }
#pragma unroll 4
        for (int j = 0; j < 64; ++j) {
            float pa = lane_bcast(h1[0], j), pb = lane_bcast(h1[1], j);
            float qa = lane_bcast(h2[0], j), qb = lane_bcast(h2[1], j);
            const float* w2row = W2 + j * 256; const float* u2row = U2 + j * 256;
#pragma unroll
            for (int g = 0; g < 4; ++g) {
                float w2v = w2row[g * 64 + lane], u2v = u2row[g * 64 + lane];
                acc2[g][0] += pa * w2v + qa * u2v;
                acc2[g][1] += pb * w2v + qb * u2v;
            }
        }
#pragma unroll
        for (int r = 0; r < 2; ++r) {
            float ig = sigm(acc2[0][r]), fg = sigm(acc2[1][r]);
            float gg = tanh_(acc2[2][r]), og = sigm(acc2[3][r]);
            c2[r] = fg * c2[r] + ig * gg; h2[r] = og * tanh_(c2[r]);
        }
    }
#pragma unroll
    for (int r = 0; r < 2; ++r) {
        float p = h2[r] * wd;
#pragma unroll
        for (int off = 32; off > 0; off >>= 1) p += __shfl_down(p, off, 64);
        if (lane == 0) out[row0 + r] = sigm(p + bdv);
    }
}

extern "C" void kernel_launch(void* const* d_in, const int* in_sizes, int n_in,
                              void* d_out, int out_size, void* d_ws, size_t ws_size,
                              hipStream_t stream) {
    const int*   tokens = (const int*)  d_in[0];
    const float* emb    = (const float*)d_in[1];
    const float* W1     = (const float*)d_in[2];
    const float* U1     = (const float*)d_in[3];
    const float* b1     = (const float*)d_in[4];
    const float* W2     = (const float*)d_in[5];
    const float* U2     = (const float*)d_in[6];
    const float* b2     = (const float*)d_in[7];
    const float* Wd     = (const float*)d_in[8];
    const float* bd     = (const float*)d_in[9];
    float* out = (float*)d_out;

    if (ws_size < (size_t)WS_NEEDED) {
        lstm_fused_fallback<<<256, 512, 0, stream>>>(tokens, emb, W1, U1, b1, W2, U2, b2, Wd, bd, out);
        return;
    }

    char* ws = (char*)d_ws;
    float* E1r = (float*)(ws + WS_E1R_OFF);
    uint*  W1p = (uint*) (ws + WS_W1P_OFF);
    uint*  B1f = (uint*) (ws + WS_B1F_OFF);
    uint*  B2f = (uint*) (ws + WS_B2F_OFF);

    prep      <<<64,  256, 0, stream>>>(W1, U1, W2, U2, W1p, B1f, B2f);
    compute_e1<<<256, 256, 0, stream>>>(emb, W1p, b1, E1r);
    lstm_mfma <<<256, 256, 0, stream>>>(tokens, E1r, (const uint4*)B1f, (const uint4*)B2f,
                                        b2, Wd, bd, out);
}